// Round 2
// baseline (192.981 us; speedup 1.0000x reference)
//
#include <hip/hip_runtime.h>
#include <stdint.h>

typedef __attribute__((ext_vector_type(8))) short short8;
typedef __attribute__((ext_vector_type(8))) unsigned short ushort8;
typedef __attribute__((ext_vector_type(4))) float floatx4;

#define W_DIM 900
#define PADW  1024
#define DDIM  1024
#define NPAD  450
#define TM    256
#define TN    128
#define BK    64

__device__ __forceinline__ unsigned short f2bf(float f) {
  unsigned int u = __builtin_bit_cast(unsigned int, f);
  u += 0x7fffu + ((u >> 16) & 1u);   // round-to-nearest-even
  return (unsigned short)(u >> 16);
}

__device__ __forceinline__ void async16(const void* g, void* l) {
  __builtin_amdgcn_global_load_lds(
      (const __attribute__((address_space(1))) void*)g,
      (__attribute__((address_space(3))) void*)l, 16, 0, 0);
}

// ---------------------------------------------------------------------------
// Convert + transpose + pad:  in[b,h,w,c] fp32 -> dst[b, w, h*256+c] bf16,
// w padded 900->1024 (zeros). grid (512, 16, 2), block 256.
// 32 B read + 16 B write per thread, fully coalesced.
// ---------------------------------------------------------------------------
__global__ void convert_kernel(const float* __restrict__ in1,
                               const float* __restrict__ in2,
                               unsigned short* __restrict__ dA,
                               unsigned short* __restrict__ dB) {
  const int t  = threadIdx.x;              // 0..255
  const int w  = blockIdx.x * 2 + (t >> 7);
  const int b  = blockIdx.y;
  const float* __restrict__ src = blockIdx.z ? in2 : in1;
  unsigned short* __restrict__ dst = blockIdx.z ? dB : dA;

  const int tt = t & 127;
  const int h  = tt >> 5;                  // 0..3
  const int c8 = (tt & 31) << 3;           // 0..248 step 8

  ushort8 o = (ushort8)0;
  if (w < W_DIM) {
    const size_t soff = (((size_t)(b * 4 + h) * W_DIM + w) * 256 + c8);
    float4 v0 = *reinterpret_cast<const float4*>(src + soff);
    float4 v1 = *reinterpret_cast<const float4*>(src + soff + 4);
    o[0] = f2bf(v0.x); o[1] = f2bf(v0.y); o[2] = f2bf(v0.z); o[3] = f2bf(v0.w);
    o[4] = f2bf(v1.x); o[5] = f2bf(v1.y); o[6] = f2bf(v1.z); o[7] = f2bf(v1.w);
  }
  const size_t doff = ((size_t)b * PADW + w) * DDIM + h * 256 + c8;
  *reinterpret_cast<ushort8*>(dst + doff) = o;
}

// ---------------------------------------------------------------------------
// Batched gram GEMM (NT, both [row][K] bf16, K=1024) + fused circular-band
// reduction. Tile 256x128, BK=64. grid (32, 16): x = it*8+jt, y = batch.
// 4 waves; wave (wm,wn) computes a 128x64 quadrant via 8x4 frags of
// v_mfma_f32_16x16x32_bf16. LDS: A 2 slabs [256][32], B 2 slabs [128][32]
// (48 KB), aliased by epilogue Ep[64][132] fp32.
// ---------------------------------------------------------------------------
__global__ __launch_bounds__(256, 2)
void gemm_band_kernel(const unsigned short* __restrict__ A,
                      const unsigned short* __restrict__ B,
                      float* __restrict__ out) {
  const int b  = blockIdx.y;
  const int it = blockIdx.x >> 3;          // 0..3
  const int jt = blockIdx.x & 7;           // 0..7

  __shared__ __align__(16) unsigned char smem[49152];
  unsigned short* As = (unsigned short*)smem;            // slabs: s*8192 + row*32
  unsigned short* Bs = (unsigned short*)smem + 16384;    // slabs: s*4096 + row*32

  const int tid  = threadIdx.x;
  const int lane = tid & 63;
  const int warp = tid >> 6;
  const int wm   = warp >> 1;              // row half (128 rows)
  const int wn   = warp & 1;               // col half (64 cols)

  const unsigned short* Ab = A + ((size_t)(b * PADW + it * TM)) * DDIM;
  const unsigned short* Bb = B + ((size_t)(b * PADW + jt * TN)) * DDIM;

  // Staging map: one async16 covers 16 rows x 32-wide k-slab.
  // lane -> row sub r = lane>>2, chunk ch = (lane&3)*8.  LDS off = base + lane*16 B.
  const int r  = lane >> 2;
  const int ch = (lane & 3) << 3;

  const unsigned short* gA[8]; unsigned short* lA[8];
#pragma unroll
  for (int g = 0; g < 4; ++g)
#pragma unroll
    for (int s = 0; s < 2; ++s) {
      const int row = warp * 64 + g * 16 + r;
      gA[g * 2 + s] = Ab + (size_t)row * DDIM + s * 32 + ch;
      lA[g * 2 + s] = As + s * 8192 + row * 32 + ch;
    }
  const unsigned short* gB[4]; unsigned short* lB[4];
#pragma unroll
  for (int g = 0; g < 2; ++g)
#pragma unroll
    for (int s = 0; s < 2; ++s) {
      const int row = warp * 32 + g * 16 + r;
      gB[g * 2 + s] = Bb + (size_t)row * DDIM + s * 32 + ch;
      lB[g * 2 + s] = Bs + s * 4096 + row * 32 + ch;
    }

  floatx4 acc[8][4];
#pragma unroll
  for (int i = 0; i < 8; ++i)
#pragma unroll
    for (int j = 0; j < 4; ++j) acc[i][j] = (floatx4)0.0f;

  const int quad = lane >> 4;
  const int r16  = lane & 15;
  // A frag (mi,kc): A[m = wm*128+mi*16+r16][k = kc*32 + quad*8 + j]
  const unsigned short* ArowBase = As + (wm * 128 + r16) * 32 + quad * 8;
  const unsigned short* BrowBase = Bs + (wn * 64 + r16) * 32 + quad * 8;

  for (int kt = 0; kt < DDIM / BK; ++kt) {
    __syncthreads();                       // prev ds_reads done before overwrite
    const int ko = kt * BK;
#pragma unroll
    for (int i = 0; i < 8; ++i) async16(gA[i] + ko, lA[i]);
#pragma unroll
    for (int i = 0; i < 4; ++i) async16(gB[i] + ko, lB[i]);
    __syncthreads();                       // drains vmcnt before barrier

    for (int kc = 0; kc < 2; ++kc) {
      short8 af[8], bf[4];
#pragma unroll
      for (int mi = 0; mi < 8; ++mi)
        af[mi] = *(const short8*)(ArowBase + kc * 8192 + mi * 16 * 32);
#pragma unroll
      for (int ni = 0; ni < 4; ++ni)
        bf[ni] = *(const short8*)(BrowBase + kc * 4096 + ni * 16 * 32);
#pragma unroll
      for (int mi = 0; mi < 8; ++mi)
#pragma unroll
        for (int ni = 0; ni < 4; ++ni)
          acc[mi][ni] = __builtin_amdgcn_mfma_f32_16x16x32_bf16(
              af[mi], bf[ni], acc[mi][ni], 0, 0, 0);
    }
  }

  // ---- Epilogue: gram[i,j] -> out[b, (i-j-450) mod 900], 4 passes of 64 rows.
  __syncthreads();                         // staging LDS dead; safe to alias
  float* Ep = (float*)smem;                // [64][132]
  const int dbase = it * TM - jt * TN - NPAD;

  for (int p = 0; p < 4; ++p) {
    if (wm == (p >> 1)) {
      const int mib = (p & 1) * 4;         // this pass covers mi in [mib, mib+4)
#pragma unroll
      for (int mo = 0; mo < 4; ++mo)
#pragma unroll
        for (int ni = 0; ni < 4; ++ni)
#pragma unroll
          for (int rr = 0; rr < 4; ++rr) {
            const int lr = mo * 16 + quad * 4 + rr;       // 0..63
            const int c  = wn * 64 + ni * 16 + r16;       // 0..127
            Ep[lr * 132 + c] = acc[mib + mo][ni][rr];
          }
    }
    __syncthreads();
    if (tid < 191) {
      const int d = tid - 127;             // i_local - j_local in [-127, 63]
      int k0 = d > 0 ? d : 0;
      int k1 = 128 + d; if (k1 > 64) k1 = 64;
      float s = 0.0f;
      for (int k = k0; k < k1; ++k) s += Ep[k * 132 + (k - d)];
      int dg = dbase + p * 64 + d;         // global i - j - 450
      int sidx = dg % W_DIM;
      if (sidx < 0) sidx += W_DIM;
      atomicAdd(&out[b * W_DIM + sidx], s);
    }
    __syncthreads();
  }
}

// ---------------------------------------------------------------------------
// Fallback (only if workspace is too small): direct fp32 computation.
// ---------------------------------------------------------------------------
__global__ void naive_kernel(const float* __restrict__ x1,
                             const float* __restrict__ x2,
                             float* __restrict__ out) {
  const int s = blockIdx.x;
  const int b = blockIdx.y;
  const int c = threadIdx.x;
  float acc = 0.0f;
  for (int h = 0; h < 4; ++h) {
    const float* p1 = x1 + (size_t)(b * 4 + h) * W_DIM * 256;
    const float* p2 = x2 + (size_t)(b * 4 + h) * W_DIM * 256;
    for (int w = 0; w < W_DIM; ++w) {
      int w1 = s + w + NPAD;
      if (w1 >= W_DIM) w1 -= W_DIM;
      if (w1 >= W_DIM) w1 -= W_DIM;
      acc += p1[(size_t)w1 * 256 + c] * p2[(size_t)w * 256 + c];
    }
  }
  for (int off = 32; off > 0; off >>= 1) acc += __shfl_down(acc, off, 64);
  __shared__ float red[4];
  if ((threadIdx.x & 63) == 0) red[threadIdx.x >> 6] = acc;
  __syncthreads();
  if (threadIdx.x == 0)
    out[b * W_DIM + s] = red[0] + red[1] + red[2] + red[3];
}

extern "C" void kernel_launch(void* const* d_in, const int* in_sizes, int n_in,
                              void* d_out, int out_size, void* d_ws, size_t ws_size,
                              hipStream_t stream) {
  const float* x1 = (const float*)d_in[0];
  const float* x2 = (const float*)d_in[1];
  float* out = (float*)d_out;

  hipMemsetAsync(d_out, 0, (size_t)out_size * sizeof(float), stream);

  const size_t need = (size_t)2 * 16 * PADW * DDIM * sizeof(unsigned short); // 64 MB
  if (ws_size >= need) {
    unsigned short* dA = (unsigned short*)d_ws;
    unsigned short* dB = dA + (size_t)16 * PADW * DDIM;
    convert_kernel<<<dim3(512, 16, 2), 256, 0, stream>>>(x1, x2, dA, dB);
    gemm_band_kernel<<<dim3(32, 16), 256, 0, stream>>>(dA, dB, out);
  } else {
    naive_kernel<<<dim3(W_DIM, 16), 256, 0, stream>>>(x1, x2, out);
  }
}

// Round 3
// 167.634 us; speedup vs baseline: 1.1512x; 1.1512x over previous
//
#include <hip/hip_runtime.h>
#include <stdint.h>

typedef __attribute__((ext_vector_type(8))) short short8;
typedef __attribute__((ext_vector_type(8))) unsigned short ushort8;
typedef __attribute__((ext_vector_type(4))) float floatx4;

#define W_DIM 900
#define NPAD  450
#define TM    256
#define TN    128
#define BK    32
#define LDST  40          // LDS row stride (elems): 32 + 8 pad -> 80 B, 16B-aligned rows,
                          // bank pattern 2-way max (free per m136)

__device__ __forceinline__ unsigned short f2bf(float f) {
  // round-half-up: bias ~2^-17 relative, negligible over 921600-term sums
  unsigned int u = __builtin_bit_cast(unsigned int, f);
  return (unsigned short)((u + 0x8000u) >> 16);
}

// ---------------------------------------------------------------------------
// Fused: fp32 inputs -> bf16 staged tiles -> gram GEMM -> circular-band reduce.
// out[b,s] = sum_{i-j-450 = s (mod 900)} <x1_i, x2_j>  (D = H*C = 1024)
//
// Tile 256x128, BK=32. Grid: 512 blocks, 1-D, swizzled x = jt*64 + it*16 + b
// so x%8 = b%8 -> all blocks of one batch share an XCD (L2 tile reuse).
// 4 waves; wave (wm,wn) computes 128x64 via 8x4 frags of mfma 16x16x32_bf16.
// Pipeline: global loads for kt+1 issued before MFMA(kt) -> in flight across
// the barrier; ds_writes wait on them at the top of kt+1.
// ---------------------------------------------------------------------------
__global__ __launch_bounds__(256, 2)
void fused_gram_band(const float* __restrict__ X1, const float* __restrict__ X2,
                     float* __restrict__ out) {
  const int x  = blockIdx.x;
  const int b  = x & 15;
  const int it = (x >> 4) & 3;         // A tile: rows it*256..
  const int jt = x >> 6;               // B tile: rows jt*128..

  __shared__ __align__(16) unsigned char smem[64 * 132 * 4];  // 33792 B
  unsigned short* As = (unsigned short*)smem;                 // [256][LDST]
  unsigned short* Bs = As + TM * LDST;                        // [128][LDST]
  // staging = 384*40*2 = 30720 B <= 33792 (epilogue Ep aliases all of it)

  const int tid  = threadIdx.x;
  const int lane = tid & 63;
  const int warp = tid >> 6;
  const int wm   = warp >> 1;
  const int wn   = warp & 1;

  // ---- staging map: lane -> (row sub = lane>>2, 8-elem chunk c8 = (lane&3)*8)
  // one step stages 16 rows x 32 k-elems; A: 4 steps (64 rows/wave), B: 2.
  const int rsub = lane >> 2;
  const int c8   = (lane & 3) << 3;

  int arow[4], brow[2];
  bool aok[4], bok[2];
#pragma unroll
  for (int s = 0; s < 4; ++s) {
    arow[s] = it * TM + warp * 64 + s * 16 + rsub;
    aok[s]  = arow[s] < W_DIM;         // padded rows (>=900) stay zero
  }
#pragma unroll
  for (int s = 0; s < 2; ++s) {
    brow[s] = jt * TN + warp * 32 + s * 16 + rsub;
    bok[s]  = brow[s] < W_DIM;
  }

  const size_t bbase = (size_t)b * 4 * W_DIM * 256;

  float4 va[4][2], vb[2][2];
  const float4 fz = make_float4(0.f, 0.f, 0.f, 0.f);

#define LOAD_SLAB(kt)                                                          \
  {                                                                            \
    const size_t koff = bbase + (size_t)((kt) >> 3) * (W_DIM * 256) +          \
                        ((kt) & 7) * 32 + c8;                                  \
    _Pragma("unroll")                                                          \
    for (int s = 0; s < 4; ++s) {                                              \
      va[s][0] = fz; va[s][1] = fz;                                            \
      if (aok[s]) {                                                            \
        const float* p = X1 + koff + (size_t)arow[s] * 256;                    \
        va[s][0] = *(const float4*)p;                                          \
        va[s][1] = *(const float4*)(p + 4);                                    \
      }                                                                        \
    }                                                                          \
    _Pragma("unroll")                                                          \
    for (int s = 0; s < 2; ++s) {                                              \
      vb[s][0] = fz; vb[s][1] = fz;                                            \
      if (bok[s]) {                                                            \
        const float* p = X2 + koff + (size_t)brow[s] * 256;                    \
        vb[s][0] = *(const float4*)p;                                          \
        vb[s][1] = *(const float4*)(p + 4);                                    \
      }                                                                        \
    }                                                                          \
  }

  floatx4 acc[8][4];
#pragma unroll
  for (int i = 0; i < 8; ++i)
#pragma unroll
    for (int j = 0; j < 4; ++j) acc[i][j] = (floatx4)0.0f;

  const int quad = lane >> 4;
  const int r16  = lane & 15;
  const unsigned short* ArowBase = As + (wm * 128 + r16) * LDST + quad * 8;
  const unsigned short* BrowBase = Bs + (wn * 64 + r16) * LDST + quad * 8;

  LOAD_SLAB(0);

  for (int kt = 0; kt < 32; ++kt) {
    __syncthreads();                   // frag reads of kt-1 done before overwrite
    // convert + write slab kt (compiler inserts vmcnt wait on va/vb here)
#pragma unroll
    for (int s = 0; s < 4; ++s) {
      ushort8 o;
      o[0] = f2bf(va[s][0].x); o[1] = f2bf(va[s][0].y);
      o[2] = f2bf(va[s][0].z); o[3] = f2bf(va[s][0].w);
      o[4] = f2bf(va[s][1].x); o[5] = f2bf(va[s][1].y);
      o[6] = f2bf(va[s][1].z); o[7] = f2bf(va[s][1].w);
      *(ushort8*)&As[(warp * 64 + s * 16 + rsub) * LDST + c8] = o;
    }
#pragma unroll
    for (int s = 0; s < 2; ++s) {
      ushort8 o;
      o[0] = f2bf(vb[s][0].x); o[1] = f2bf(vb[s][0].y);
      o[2] = f2bf(vb[s][0].z); o[3] = f2bf(vb[s][0].w);
      o[4] = f2bf(vb[s][1].x); o[5] = f2bf(vb[s][1].y);
      o[6] = f2bf(vb[s][1].z); o[7] = f2bf(vb[s][1].w);
      *(ushort8*)&Bs[(warp * 32 + s * 16 + rsub) * LDST + c8] = o;
    }
    __syncthreads();                   // writes visible

    if (kt < 31) LOAD_SLAB(kt + 1);    // in flight across MFMA + next barrier

    short8 af[8], bf[4];
#pragma unroll
    for (int mi = 0; mi < 8; ++mi)
      af[mi] = *(const short8*)(ArowBase + mi * 16 * LDST);
#pragma unroll
    for (int ni = 0; ni < 4; ++ni)
      bf[ni] = *(const short8*)(BrowBase + ni * 16 * LDST);
#pragma unroll
    for (int mi = 0; mi < 8; ++mi)
#pragma unroll
      for (int ni = 0; ni < 4; ++ni)
        acc[mi][ni] = __builtin_amdgcn_mfma_f32_16x16x32_bf16(
            af[mi], bf[ni], acc[mi][ni], 0, 0, 0);
  }

  // ---- Epilogue: gram[i,j] -> out[b, (i-j-450) mod 900]; 4 passes of 64 rows.
  __syncthreads();
  float* Ep = (float*)smem;            // [64][132]
  const int dbase = it * TM - jt * TN - NPAD;

  for (int p = 0; p < 4; ++p) {
    if (wm == (p >> 1)) {
      const int mib = (p & 1) * 4;
#pragma unroll
      for (int mo = 0; mo < 4; ++mo)
#pragma unroll
        for (int ni = 0; ni < 4; ++ni)
#pragma unroll
          for (int rr = 0; rr < 4; ++rr) {
            const int lr = mo * 16 + quad * 4 + rr;       // tile row p*64 + lr
            const int c  = wn * 64 + ni * 16 + r16;       // tile col
            Ep[lr * 132 + c] = acc[mib + mo][ni][rr];
          }
    }
    __syncthreads();
    if (tid < 191) {
      const int d = tid - 127;         // lr - c in [-127, 63]
      int k0 = d > 0 ? d : 0;
      int k1 = 128 + d; if (k1 > 64) k1 = 64;
      float s = 0.0f;
      for (int k = k0; k < k1; ++k) s += Ep[k * 132 + (k - d)];
      int dg = dbase + p * 64 + d;     // in (-1800, 1800)
      int sidx = dg % W_DIM;
      if (sidx < 0) sidx += W_DIM;
      atomicAdd(&out[b * W_DIM + sidx], s);
    }
    __syncthreads();
  }
}

extern "C" void kernel_launch(void* const* d_in, const int* in_sizes, int n_in,
                              void* d_out, int out_size, void* d_ws, size_t ws_size,
                              hipStream_t stream) {
  const float* x1 = (const float*)d_in[0];
  const float* x2 = (const float*)d_in[1];
  float* out = (float*)d_out;

  hipMemsetAsync(d_out, 0, (size_t)out_size * sizeof(float), stream);
  fused_gram_band<<<dim3(512), 256, 0, stream>>>(x1, x2, out);
}